// Round 10
// baseline (892.772 us; speedup 1.0000x reference)
//
#include <hip/hip_runtime.h>
#include <stdint.h>

// HashEncoder (Instant-NGP / HashNeRF): 1M points, 16 levels, 2 feats, 2^19 table.
// R11: verified-fast gather structure + direct scattered output writes.
// Evidence ladder: original k_enc (single launch, blockIdx.y=level) = 365us — the
// ONLY fast gather config measured (level-major dispatch order keeps ~1-2 tables
// hot per XCD-L2, zero launch gaps). R8 in-thread loop: FETCH 2.0GB (drift).
// R9 XCD-pairing: FETCH 1.26GB + imbalance, 740us. R10 16 launches: locality OK
// but +250us of launch gap/ramp/tail, 707us.
// This round: keep the 365us gather EXACTLY; kill the transpose by storing each
// level's float2 straight to out[p*32 + 2l] (8B nt store, stride 32B). Each 8B
// slot written once; 4x sector amp -> ~512MB writes (~+60us) replaces the old
// ~190us ws round-trip + second kernel.
// Predicted: WRITE ~500-540MB, FETCH 0.5-1.0GB, kernel 430-470us.
// R12/R13: unchanged — R11 never ran (broker timeout, then container failure);
// need its measurement before any further change.

static constexpr int NP = 1048576;
static constexpr int NL = 16;
static constexpr int TPB = 256;
static constexpr uint32_t HMASK = (1u << 19) - 1u;

typedef float f32x2 __attribute__((ext_vector_type(2)));

// res_i = floor(16 * b^i), b = f32(exp((ln512-ln16)/15)) = 1.2599210739135742
// Verified: absmax 2.4e-7 vs reference (R8/R9/R10 runs).
__constant__ float c_res[NL] = {16.f, 20.f, 25.f, 32.f, 40.f, 50.f, 64.f, 80.f,
                                101.f, 128.f, 161.f, 203.f, 256.f, 322.f, 406.f, 512.f};

__device__ __forceinline__ float2 enc_one(
    float x0, float x1, float x2,
    float b0, float b1, float b2,
    float B0, float B1, float B2,
    const float2* __restrict__ tab, float res, float gate)
{
    // index path must be bit-exact vs numpy f32: sub/div/floor only
    float g0 = (B0 - b0) / res;
    float g1 = (B1 - b1) / res;
    float g2 = (B2 - b2) / res;
    float xc0 = fminf(fmaxf(x0, b0), B0);
    float xc1 = fminf(fmaxf(x1, b1), B1);
    float xc2 = fminf(fmaxf(x2, b2), B2);
    float f0 = floorf((xc0 - b0) / g0);
    float f1 = floorf((xc1 - b1) / g1);
    float f2 = floorf((xc2 - b2) / g2);
    // interpolation weights use RAW x (per reference)
    float v0 = f0 * g0 + b0;
    float v1 = f1 * g1 + b1;
    float v2 = f2 * g2 + b2;
    float w0 = (x0 - v0) / ((v0 + g0) - v0);
    float w1 = (x1 - v1) / ((v1 + g1) - v1);
    float w2 = (x2 - v2) / ((v2 + g2) - v2);

    uint32_t u0 = (uint32_t)(int)f0;
    uint32_t u1 = (uint32_t)(int)f1;
    uint32_t u2 = (uint32_t)(int)f2;
    uint32_t ya = u1 * 2654435761u, yb = (u1 + 1u) * 2654435761u;
    uint32_t za = u2 * 805459861u,  zb = (u2 + 1u) * 805459861u;
    uint32_t xa = u0, xb = u0 + 1u;

    // corner index = i*4 + j*2 + k (i on x, j on y, k on z)
    float2 e000 = tab[(xa ^ ya ^ za) & HMASK];
    float2 e001 = tab[(xa ^ ya ^ zb) & HMASK];
    float2 e010 = tab[(xa ^ yb ^ za) & HMASK];
    float2 e011 = tab[(xa ^ yb ^ zb) & HMASK];
    float2 e100 = tab[(xb ^ ya ^ za) & HMASK];
    float2 e101 = tab[(xb ^ ya ^ zb) & HMASK];
    float2 e110 = tab[(xb ^ yb ^ za) & HMASK];
    float2 e111 = tab[(xb ^ yb ^ zb) & HMASK];

    float s0 = 1.f - w0, s1 = 1.f - w1, s2 = 1.f - w2;
    float cx00x = e000.x * s0 + e100.x * w0, cx00y = e000.y * s0 + e100.y * w0;
    float cx01x = e001.x * s0 + e101.x * w0, cx01y = e001.y * s0 + e101.y * w0;
    float cx10x = e010.x * s0 + e110.x * w0, cx10y = e010.y * s0 + e110.y * w0;
    float cx11x = e011.x * s0 + e111.x * w0, cx11y = e011.y * s0 + e111.y * w0;
    float c0x = cx00x * s1 + cx10x * w1, c0y = cx00y * s1 + cx10y * w1;
    float c1x = cx01x * s1 + cx11x * w1, c1y = cx01y * s1 + cx11y * w1;
    float ox = c0x * s2 + c1x * w2;
    float oy = c0y * s2 + c1y * w2;
    return make_float2(ox * gate, oy * gate);
}

// Original verified gather structure: thread = (point, level), blockIdx.y = level.
// Level-major dispatch order -> ~1-2 tables hot per XCD L2 at any instant.
// Store goes straight to the final out slot: float2 at out[p*32 + 2l]
// (= f32x2 index p*16 + l). Non-temporal: the 512MB write stream must not evict
// the resident hash table from L2.
__global__ __launch_bounds__(TPB) void k_enc_direct(
    const float* __restrict__ x, const float* __restrict__ emb,
    const float* __restrict__ lw, const float* __restrict__ bmin,
    const float* __restrict__ bmax, f32x2* __restrict__ out)
{
    int p = blockIdx.x * TPB + threadIdx.x;
    int l = blockIdx.y;

    // streamed inputs: non-temporal so they don't evict the resident table
    float x0 = __builtin_nontemporal_load(x + 3 * p + 0);
    float x1 = __builtin_nontemporal_load(x + 3 * p + 1);
    float x2 = __builtin_nontemporal_load(x + 3 * p + 2);
    float b0 = bmin[0], b1 = bmin[1], b2 = bmin[2];
    float B0 = bmax[0], B1 = bmax[1], B2 = bmax[2];

    float res = c_res[l];
    float gate = 1.0f / (1.0f + expf(-lw[l]));
    const float2* tab = (const float2*)(emb + ((size_t)l << 20));

    float2 r = enc_one(x0, x1, x2, b0, b1, b2, B0, B1, B2, tab, res, gate);

    f32x2 v = {r.x, r.y};
    __builtin_nontemporal_store(v, out + (size_t)p * 16 + l);
}

extern "C" void kernel_launch(void* const* d_in, const int* in_sizes, int n_in,
                              void* d_out, int out_size, void* d_ws, size_t ws_size,
                              hipStream_t stream) {
    const float* x    = (const float*)d_in[0];
    const float* emb  = (const float*)d_in[1];
    const float* lw   = (const float*)d_in[2];
    const float* bmin = (const float*)d_in[3];
    const float* bmax = (const float*)d_in[4];
    (void)d_ws; (void)ws_size;

    dim3 grid(NP / TPB, NL);
    k_enc_direct<<<grid, TPB, 0, stream>>>(x, emb, lw, bmin, bmax, (f32x2*)d_out);
}

// Round 16
// 547.676 us; speedup vs baseline: 1.6301x; 1.6301x over previous
//
#include <hip/hip_runtime.h>
#include <stdint.h>

// HashEncoder (Instant-NGP / HashNeRF): 1M points, 16 levels, 2 feats, 2^19 table.
// R16: verified k_enc gather (unchanged) + block-contiguous ws layout for k_tr.
// Session evidence: R8 fused loop FETCH 2.0GB (drift); R9 XCD pairing 1.26GB +
// imbalance (740us); R10 16 launches +250us overhead (707); R11 direct scatter:
// write-amp model exact (523MB) but nt+sub-32B stores ~3x traffic cost (780us).
// Old two-kernel split: k_enc 365us (verified) + k_tr ~190us vs 41us floor.
// k_tr theory: old ws[l][p] layout made Phase A read 16 streams strided 8MB
// (256 concurrent streams/CU at 16 waves/CU) — strided-stream underperformance.
// Fix: ws[chunk][level][point-in-chunk], chunk=256 points. k_enc store stays
// fully coalesced (contiguous 512B/wave: ws[bx*4096 + l*256 + t]); k_tr reads
// its 32KB chunk contiguously and writes 32KB contiguously = pure streaming.
// Writer (pb,l) and reader pb land on same XCD (4096%8==0) -> dirty tail is
// local-L2-hit.
// Predicted: k_enc 355-400us FETCH 0.3-0.6GB WRITE 131MB; k_tr 45-70us
// FETCH 90-131MB WRITE 131MB; total ~420-470us vs 554.7 baseline.

static constexpr int NP = 1048576;
static constexpr int NL = 16;
static constexpr int TPB = 256;
static constexpr uint32_t HMASK = (1u << 19) - 1u;

typedef float f32x4 __attribute__((ext_vector_type(4)));

// res_i = floor(16 * b^i), b = f32(exp((ln512-ln16)/15)) = 1.2599210739135742
// Verified: absmax 2.4e-7 vs reference (R8-R11 runs).
__constant__ float c_res[NL] = {16.f, 20.f, 25.f, 32.f, 40.f, 50.f, 64.f, 80.f,
                                101.f, 128.f, 161.f, 203.f, 256.f, 322.f, 406.f, 512.f};

__device__ __forceinline__ float2 enc_one(
    float x0, float x1, float x2,
    float b0, float b1, float b2,
    float B0, float B1, float B2,
    const float2* __restrict__ tab, float res, float gate)
{
    // index path must be bit-exact vs numpy f32: sub/div/floor only
    float g0 = (B0 - b0) / res;
    float g1 = (B1 - b1) / res;
    float g2 = (B2 - b2) / res;
    float xc0 = fminf(fmaxf(x0, b0), B0);
    float xc1 = fminf(fmaxf(x1, b1), B1);
    float xc2 = fminf(fmaxf(x2, b2), B2);
    float f0 = floorf((xc0 - b0) / g0);
    float f1 = floorf((xc1 - b1) / g1);
    float f2 = floorf((xc2 - b2) / g2);
    // interpolation weights use RAW x (per reference)
    float v0 = f0 * g0 + b0;
    float v1 = f1 * g1 + b1;
    float v2 = f2 * g2 + b2;
    float w0 = (x0 - v0) / ((v0 + g0) - v0);
    float w1 = (x1 - v1) / ((v1 + g1) - v1);
    float w2 = (x2 - v2) / ((v2 + g2) - v2);

    uint32_t u0 = (uint32_t)(int)f0;
    uint32_t u1 = (uint32_t)(int)f1;
    uint32_t u2 = (uint32_t)(int)f2;
    uint32_t ya = u1 * 2654435761u, yb = (u1 + 1u) * 2654435761u;
    uint32_t za = u2 * 805459861u,  zb = (u2 + 1u) * 805459861u;
    uint32_t xa = u0, xb = u0 + 1u;

    // corner index = i*4 + j*2 + k (i on x, j on y, k on z)
    float2 e000 = tab[(xa ^ ya ^ za) & HMASK];
    float2 e001 = tab[(xa ^ ya ^ zb) & HMASK];
    float2 e010 = tab[(xa ^ yb ^ za) & HMASK];
    float2 e011 = tab[(xa ^ yb ^ zb) & HMASK];
    float2 e100 = tab[(xb ^ ya ^ za) & HMASK];
    float2 e101 = tab[(xb ^ ya ^ zb) & HMASK];
    float2 e110 = tab[(xb ^ yb ^ za) & HMASK];
    float2 e111 = tab[(xb ^ yb ^ zb) & HMASK];

    float s0 = 1.f - w0, s1 = 1.f - w1, s2 = 1.f - w2;
    float cx00x = e000.x * s0 + e100.x * w0, cx00y = e000.y * s0 + e100.y * w0;
    float cx01x = e001.x * s0 + e101.x * w0, cx01y = e001.y * s0 + e101.y * w0;
    float cx10x = e010.x * s0 + e110.x * w0, cx10y = e010.y * s0 + e110.y * w0;
    float cx11x = e011.x * s0 + e111.x * w0, cx11y = e011.y * s0 + e111.y * w0;
    float c0x = cx00x * s1 + cx10x * w1, c0y = cx00y * s1 + cx10y * w1;
    float c1x = cx01x * s1 + cx11x * w1, c1y = cx01y * s1 + cx11y * w1;
    float ox = c0x * s2 + c1x * w2;
    float oy = c0y * s2 + c1y * w2;
    return make_float2(ox * gate, oy * gate);
}

// Kernel 1: thread = (point, level). blockIdx.y = level -> level-major dispatch
// order, each XCD L2 holds ~one 4MiB table at a time (verified-fast structure).
// ws layout: [chunk=p>>8][level][point-in-chunk] -> store index bx*4096+l*256+t,
// contiguous 512B per wave (fully coalesced, same class as verified version).
__global__ __launch_bounds__(TPB) void k_enc(
    const float* __restrict__ x, const float* __restrict__ emb,
    const float* __restrict__ lw, const float* __restrict__ bmin,
    const float* __restrict__ bmax, float2* __restrict__ ws)
{
    int t = threadIdx.x;
    int p = blockIdx.x * TPB + t;
    int l = blockIdx.y;
    float x0 = x[3 * p + 0], x1 = x[3 * p + 1], x2 = x[3 * p + 2];
    float b0 = bmin[0], b1 = bmin[1], b2 = bmin[2];
    float B0 = bmax[0], B1 = bmax[1], B2 = bmax[2];
    float res = c_res[l];
    float gate = 1.0f / (1.0f + expf(-lw[l]));
    const float2* tab = (const float2*)(emb + ((size_t)l << 20));
    float2 r = enc_one(x0, x1, x2, b0, b1, b2, B0, B1, B2, tab, res, gate);
    ws[(size_t)blockIdx.x * 4096 + l * 256 + t] = r;
}

// Kernel 2: transpose, now pure streaming. Block = 256 points = one 32KB chunk.
// Phase A: 8 f32x4 loads/thread from the block's CONTIGUOUS chunk -> LDS.
//   f32x4 j covers float2s (2j,2j+1): level l=j>>7, points u=2*(j&127), u+1.
// Phase B: 8 contiguous f32x4 stores/thread (identical to verified k_tr).
__global__ __launch_bounds__(TPB) void k_tr(
    const f32x4* __restrict__ ws4, f32x4* __restrict__ out)
{
    __shared__ float2 s[256][17];
    int t = threadIdx.x;
    size_t b = (size_t)blockIdx.x;
#pragma unroll
    for (int k = 0; k < 8; ++k) {
        int j = k * 256 + t;          // 0..2047 f32x4 within chunk
        f32x4 v = ws4[b * 2048 + (size_t)j];
        int l = j >> 7;               // level
        int u = 2 * (j & 127);        // first of two points
        s[u][l]     = make_float2(v.x, v.y);
        s[u + 1][l] = make_float2(v.z, v.w);
    }
    __syncthreads();
    size_t p0 = b * 256;
#pragma unroll
    for (int k = 0; k < 8; ++k) {
        int n = k * 256 + t;          // 0..2047: f32x4 index within block tile
        int q = n >> 3;               // local point
        int j = n & 7;                // quad within point
        float2 a = s[q][2 * j];
        float2 c = s[q][2 * j + 1];
        f32x4 v = {a.x, a.y, c.x, c.y};
        out[p0 * 8 + (size_t)n] = v;
    }
}

// Fallback if ws too small: R8 fused kernel (verified correct, 615us).
__global__ __launch_bounds__(TPB) void k_enc_fused(
    const float* __restrict__ x, const float* __restrict__ emb,
    const float* __restrict__ lw, const float* __restrict__ bmin,
    const float* __restrict__ bmax, f32x4* __restrict__ out)
{
    __shared__ float2 s[TPB][9];
    int t = threadIdx.x;
    size_t p0 = (size_t)blockIdx.x * TPB;
    int p = (int)p0 + t;

    float x0 = x[3 * p + 0], x1 = x[3 * p + 1], x2 = x[3 * p + 2];
    float b0 = bmin[0], b1 = bmin[1], b2 = bmin[2];
    float B0 = bmax[0], B1 = bmax[1], B2 = bmax[2];

#pragma unroll
    for (int ph = 0; ph < 2; ++ph) {
        if (ph) __syncthreads();
#pragma unroll
        for (int m = 0; m < 8; ++m) {
            int l = ph * 8 + m;
            float res = c_res[l];
            float gate = 1.0f / (1.0f + expf(-lw[l]));
            const float2* tab = (const float2*)(emb + ((size_t)l << 20));
            s[t][m] = enc_one(x0, x1, x2, b0, b1, b2, B0, B1, B2, tab, res, gate);
        }
        __syncthreads();
#pragma unroll
        for (int k = 0; k < 4; ++k) {
            int n = k * TPB + t;
            int q = n >> 2;
            int j = n & 3;
            float2 a = s[q][2 * j];
            float2 c = s[q][2 * j + 1];
            f32x4 v = {a.x, a.y, c.x, c.y};
            out[(p0 + (size_t)q) * 8 + ph * 4 + j] = v;
        }
    }
}

extern "C" void kernel_launch(void* const* d_in, const int* in_sizes, int n_in,
                              void* d_out, int out_size, void* d_ws, size_t ws_size,
                              hipStream_t stream) {
    const float* x    = (const float*)d_in[0];
    const float* emb  = (const float*)d_in[1];
    const float* lw   = (const float*)d_in[2];
    const float* bmin = (const float*)d_in[3];
    const float* bmax = (const float*)d_in[4];

    const size_t ws_need = (size_t)NL * NP * sizeof(float2);  // 128 MB
    if (ws_size >= ws_need) {
        dim3 grid1(NP / TPB, NL);
        k_enc<<<grid1, TPB, 0, stream>>>(x, emb, lw, bmin, bmax, (float2*)d_ws);
        k_tr<<<NP / 256, TPB, 0, stream>>>((const f32x4*)d_ws, (f32x4*)d_out);
    } else {
        k_enc_fused<<<NP / TPB, TPB, 0, stream>>>(
            x, emb, lw, bmin, bmax, (f32x4*)d_out);
    }
}